// Round 12
// baseline (262.826 us; speedup 1.0000x reference)
//
#include <hip/hip_runtime.h>

#define NEQ_   4096
#define XDIM_  6144
#define EEDGES 32768

typedef __bf16 bf16x8 __attribute__((ext_vector_type(8)));
typedef float  f32x4  __attribute__((ext_vector_type(4)));

__device__ __forceinline__ unsigned short f2bf(float f) {
    union { float f; unsigned u; } v; v.f = f;
    unsigned r = v.u + 0x7FFFu + ((v.u >> 16) & 1u);   // RNE
    return (unsigned short)(r >> 16);
}

__device__ __forceinline__ void gll16(const void* g, void* l) {
    __builtin_amdgcn_global_load_lds(
        (const __attribute__((address_space(1))) unsigned int*)g,
        (__attribute__((address_space(3))) unsigned int*)l, 16, 0, 0);
}

// ---- v4 tcvt tile body (VERIFIED): one 64k x 64n tile, W[K][N] f32 -> Wt[N][K] bf16.
__device__ __forceinline__ void tcvt_tile(const float* __restrict__ W,
                                          unsigned short* __restrict__ Wt,
                                          int K, int N, int kb, int nb,
                                          unsigned int* T, int t)
{
    const int q = t >> 4, i4 = t & 15;
    const float* Wp = W + (size_t)kb * N + nb + i4 * 4;
    f32x4 f[4];
    #pragma unroll
    for (int r = 0; r < 2; ++r)
        #pragma unroll
        for (int p = 0; p < 2; ++p)
            f[r * 2 + p] = *(const f32x4*)(Wp + (size_t)(2 * q + 32 * r + p) * N);

    #pragma unroll
    for (int r = 0; r < 2; ++r)
        #pragma unroll
        for (int j = 0; j < 4; ++j) {
            unsigned lo = f2bf(f[2 * r][j]);
            unsigned hi = f2bf(f[2 * r + 1][j]);
            T[(4 * i4 + j) * 33 + q + 16 * r] = lo | (hi << 16);
        }
    __syncthreads();

    const int rn = t >> 2, c4 = t & 3;
    union { unsigned u[8]; uint4 v[2]; } o;
    #pragma unroll
    for (int s = 0; s < 2; ++s)
        #pragma unroll
        for (int j = 0; j < 4; ++j)
            o.u[s * 4 + j] = T[rn * 33 + 16 * s + 4 * c4 + j];
    unsigned short* dst = Wt + (size_t)(nb + rn) * K + kb + 8 * c4;
    *(uint4*)(dst)      = o.v[0];
    *(uint4*)(dst + 32) = o.v[1];
}

// ---- GCN prologue (small, serial, atomics kept in standalone kernels) ----

__global__ void gcn_init(int* __restrict__ c1, float* __restrict__ S) {
    int i = blockIdx.x * 256 + threadIdx.x;
    if (i < NEQ_) { c1[i] = 0; S[i] = 0.f; }
}

__global__ void gcn_hist(const int* __restrict__ dst, int* __restrict__ c1) {
    int e = blockIdx.x * 256 + threadIdx.x;
    if (e < EEDGES) atomicAdd(&c1[dst[e]], 1);
}

__global__ void gcn_scatter(const int* __restrict__ src, const int* __restrict__ dst,
                            const float* __restrict__ x, const int* __restrict__ c1,
                            float* __restrict__ S) {
    int e = blockIdx.x * 256 + threadIdx.x;
    if (e < EEDGES) {
        int s = src[e], d = dst[e];
        float xf = x[(size_t)(s & 511) * XDIM_ + (s >> 9)];
        float ds = rsqrtf(512.f * (float)c1[s] + 1.f);
        atomicAdd(&S[d], ds * xf);
    }
}

// ---- build_z (12288 blocks) + W1 transpose (3072 tiles) in one grid (VERIFIED r11) ----
__global__ __launch_bounds__(256)
void bz_tcvt1(const float* __restrict__ x, const int* __restrict__ c1,
              const float* __restrict__ S,
              const float* __restrict__ gw, const float* __restrict__ gb,
              unsigned short* __restrict__ z,
              const float* __restrict__ W1, unsigned short* __restrict__ W1t)
{
    __shared__ unsigned int T[64 * 33];   // 8448 B (tcvt branch only)
    const int bid = blockIdx.x, t = threadIdx.x;
    if (bid < 12288) {
        int i = (bid % 24) * 256 + t;
        int b = bid / 24;
        float xv = x[(size_t)b * XDIM_ + i];
        float v;
        if (i >= NEQ_) {
            v = xv;
        } else {
            float w00 = gw[0], b0 = gb[0];
            if (i >= 8) {
                v = fmaxf(w00 * xv + b0, 0.f);
            } else {
                int n = i * 512 + b;
                float deg = 512.f * (float)c1[n] + 1.f;
                float dn = rsqrtf(deg);
                float outv = w00 * (512.f * dn * S[n] + xv / deg);
                v = fmaxf(outv + b0, 0.f);
            }
        }
        z[(size_t)b * XDIM_ + i] = f2bf(v);
        return;
    }
    int b2 = bid - 12288;
    tcvt_tile(W1, W1t, 6144, 2048, (b2 % 96) * 64, (b2 / 96) * 64, T, t);
}

// ---- L1 GEMM 64m x 128n tile (1024 blocks = 4/CU, bid<1024 dispatch first)
// + W2/W3 transpose (3072 tiles) filling CU slack.
// Staging: A = gemm64's verified 2-call pattern, B = gemm128's verified 4-call
// pattern. 24KB LDS -> 6 blocks/CU cap; occupancy fix for the r11-measured
// 17%-occupancy / 2-blocks/CU wall. ----
__global__ __launch_bounds__(256)
void gemmL1_tcvt23(const unsigned short* __restrict__ A,   // z [512][6144]
                   const unsigned short* __restrict__ Bt,  // W1t [2048][6144]
                   float* __restrict__ P,                   // [8][512][2048]
                   const float* __restrict__ W2, unsigned short* __restrict__ W2t,
                   const float* __restrict__ W3, unsigned short* __restrict__ W3t)
{
    __shared__ unsigned short As[2 * 64 * 32];   // 8 KB
    __shared__ unsigned short Bs[2 * 128 * 32];  // 16 KB
    const int bid = blockIdx.x;
    if (bid >= 1024) {
        unsigned int* T = (unsigned int*)Bs;     // 8448 B <= 16 KB
        int b2 = bid - 1024;
        if (b2 < 1024)
            tcvt_tile(W2, W2t, 2048, 2048, (b2 % 32) * 64, (b2 / 32) * 64, T, threadIdx.x);
        else {
            int b3 = b2 - 1024;
            tcvt_tile(W3, W3t, 2048, 4096, (b3 % 32) * 64, (b3 / 32) * 64, T, threadIdx.x);
        }
        return;
    }
    constexpr int K = 6144, N = 2048, KCHUNK = 768;
    const int tid = threadIdx.x, lane = tid & 63, wave = tid >> 6;
    const int m0 = (bid & 7) * 64;              // 8 m-tiles
    const int n0 = ((bid >> 3) & 15) * 128;     // 16 n-tiles
    const int sidx = bid >> 7;                  // 8 split-K slices
    const int wm = (wave >> 1) * 32, wn = (wave & 1) * 64;
    const int fr = lane & 15, fko = (lane >> 4) * 8;
    const int k0 = sidx * KCHUNK, k1 = k0 + KCHUNK;

    const int srow = tid >> 2;                  // 0..63
    const int sko  = (tid & 3) * 8;
    const size_t aoff  = (size_t)(m0 + srow) * K + sko;
    const size_t boff0 = (size_t)(n0 + srow) * K + sko;
    const size_t boff1 = (size_t)(n0 + 64 + srow) * K + sko;
    unsigned short* asl = &As[srow * 32 + sko];   // byte = t*16 (wave-uniform base)
    unsigned short* bsl = &Bs[srow * 32 + sko];

    f32x4 acc[2][4] = {};

    for (int kk = k0; kk < k1; kk += 64) {
        gll16(A + aoff + kk,        asl);            // A rows 0..63, k-half 0
        gll16(A + aoff + kk + 32,   asl + 2048);     // A rows 0..63, k-half 1
        gll16(Bt + boff0 + kk,      bsl);            // B rows 0..63,  kh0
        gll16(Bt + boff1 + kk,      bsl + 2048);     // B rows 64..127,kh0
        gll16(Bt + boff0 + kk + 32, bsl + 4096);     // B rows 0..63,  kh1
        gll16(Bt + boff1 + kk + 32, bsl + 6144);     // B rows 64..127,kh1
        __syncthreads();

        bf16x8 af[2][2], bfr[4][2];
        #pragma unroll
        for (int kh = 0; kh < 2; ++kh) {
            #pragma unroll
            for (int t = 0; t < 2; ++t)
                af[t][kh]  = *(const bf16x8*)(&As[kh * 2048 + (wm + t * 16 + fr) * 32 + fko]);
            #pragma unroll
            for (int u = 0; u < 4; ++u)
                bfr[u][kh] = *(const bf16x8*)(&Bs[kh * 4096 + (wn + u * 16 + fr) * 32 + fko]);
        }
        #pragma unroll
        for (int kh = 0; kh < 2; ++kh)
            #pragma unroll
            for (int mt = 0; mt < 2; ++mt)
                #pragma unroll
                for (int nt = 0; nt < 4; ++nt)
                    acc[mt][nt] = __builtin_amdgcn_mfma_f32_16x16x32_bf16(
                        af[mt][kh], bfr[nt][kh], acc[mt][nt], 0, 0, 0);

        __syncthreads();
    }

    float* Pp = P + (size_t)sidx * 512 * N;
    const int col = lane & 15, qr = (lane >> 4) * 4;
    #pragma unroll
    for (int mt = 0; mt < 2; ++mt)
    #pragma unroll
    for (int nt = 0; nt < 4; ++nt) {
        int gm = m0 + wm + mt * 16 + qr;
        int gn = n0 + wn + nt * 16 + col;
        #pragma unroll
        for (int r = 0; r < 4; ++r)
            Pp[(size_t)(gm + r) * N + gn] = acc[mt][nt][r];
    }
}

// ---- standalone 64m x 128n GEMM (L3: grid (M/64, N/128, S) = 1024 blocks = 4/CU) ----
__global__ __launch_bounds__(256)
void gemm64x128(const unsigned short* __restrict__ A,   // [M][K] bf16
                const unsigned short* __restrict__ Bt,  // [N][K] bf16
                float* __restrict__ P,                  // [S][M][N] f32
                int M, int N, int K, int kChunk)
{
    __shared__ unsigned short As[2 * 64 * 32];   // 8 KB
    __shared__ unsigned short Bs[2 * 128 * 32];  // 16 KB
    const int tid = threadIdx.x, lane = tid & 63, wave = tid >> 6;
    const int m0 = blockIdx.x * 64, n0 = blockIdx.y * 128;
    const int wm = (wave >> 1) * 32, wn = (wave & 1) * 64;
    const int fr = lane & 15, fko = (lane >> 4) * 8;
    const int k0 = blockIdx.z * kChunk, k1 = k0 + kChunk;

    const int srow = tid >> 2;
    const int sko  = (tid & 3) * 8;
    const size_t aoff  = (size_t)(m0 + srow) * K + sko;
    const size_t boff0 = (size_t)(n0 + srow) * K + sko;
    const size_t boff1 = (size_t)(n0 + 64 + srow) * K + sko;
    unsigned short* asl = &As[srow * 32 + sko];
    unsigned short* bsl = &Bs[srow * 32 + sko];

    f32x4 acc[2][4] = {};

    for (int kk = k0; kk < k1; kk += 64) {
        gll16(A + aoff + kk,        asl);
        gll16(A + aoff + kk + 32,   asl + 2048);
        gll16(Bt + boff0 + kk,      bsl);
        gll16(Bt + boff1 + kk,      bsl + 2048);
        gll16(Bt + boff0 + kk + 32, bsl + 4096);
        gll16(Bt + boff1 + kk + 32, bsl + 6144);
        __syncthreads();

        bf16x8 af[2][2], bfr[4][2];
        #pragma unroll
        for (int kh = 0; kh < 2; ++kh) {
            #pragma unroll
            for (int t = 0; t < 2; ++t)
                af[t][kh]  = *(const bf16x8*)(&As[kh * 2048 + (wm + t * 16 + fr) * 32 + fko]);
            #pragma unroll
            for (int u = 0; u < 4; ++u)
                bfr[u][kh] = *(const bf16x8*)(&Bs[kh * 4096 + (wn + u * 16 + fr) * 32 + fko]);
        }
        #pragma unroll
        for (int kh = 0; kh < 2; ++kh)
            #pragma unroll
            for (int mt = 0; mt < 2; ++mt)
                #pragma unroll
                for (int nt = 0; nt < 4; ++nt)
                    acc[mt][nt] = __builtin_amdgcn_mfma_f32_16x16x32_bf16(
                        af[mt][kh], bfr[nt][kh], acc[mt][nt], 0, 0, 0);

        __syncthreads();
    }

    float* Pp = P + (size_t)blockIdx.z * M * N;
    const int col = lane & 15, qr = (lane >> 4) * 4;
    #pragma unroll
    for (int mt = 0; mt < 2; ++mt)
    #pragma unroll
    for (int nt = 0; nt < 4; ++nt) {
        int gm = m0 + wm + mt * 16 + qr;
        int gn = n0 + wn + nt * 16 + col;
        #pragma unroll
        for (int r = 0; r < 4; ++r)
            Pp[(size_t)(gm + r) * N + gn] = acc[mt][nt][r];
    }
}

// ---- 64x64-tile MFMA GEMM (VERIFIED; L2) ----
__global__ __launch_bounds__(256)
void gemm64(const unsigned short* __restrict__ A,   // [M][K] bf16
            const unsigned short* __restrict__ Bt,  // [N][K] bf16
            float* __restrict__ P,                  // [S][M][N] f32
            int M, int N, int K, int kChunk)
{
    __shared__ unsigned short As[2 * 64 * 32];   // 8 KB
    __shared__ unsigned short Bs[2 * 64 * 32];   // 8 KB
    const int tid = threadIdx.x, lane = tid & 63, wave = tid >> 6;
    const int m0 = blockIdx.x * 64, n0 = blockIdx.y * 64;
    const int wm = (wave >> 1) * 32, wn = (wave & 1) * 32;
    const int fr = lane & 15, fko = (lane >> 4) * 8;
    const int k0 = blockIdx.z * kChunk, k1 = k0 + kChunk;

    const int srow = tid >> 2;
    const int sko  = (tid & 3) * 8;
    const size_t aoff = (size_t)(m0 + srow) * K + sko;
    const size_t boff = (size_t)(n0 + srow) * K + sko;
    unsigned short* asl0 = &As[srow * 32 + sko];
    unsigned short* asl1 = &As[2048 + srow * 32 + sko];
    unsigned short* bsl0 = &Bs[srow * 32 + sko];
    unsigned short* bsl1 = &Bs[2048 + srow * 32 + sko];

    f32x4 acc[2][2] = {};

    for (int kk = k0; kk < k1; kk += 64) {
        gll16(A + aoff + kk,      asl0);
        gll16(A + aoff + kk + 32, asl1);
        gll16(Bt + boff + kk,      bsl0);
        gll16(Bt + boff + kk + 32, bsl1);
        __syncthreads();

        bf16x8 af[2][2], bfr[2][2];
        #pragma unroll
        for (int kh = 0; kh < 2; ++kh)
            #pragma unroll
            for (int t = 0; t < 2; ++t) {
                af[t][kh]  = *(const bf16x8*)(&As[kh * 2048 + (wm + t * 16 + fr) * 32 + fko]);
                bfr[t][kh] = *(const bf16x8*)(&Bs[kh * 2048 + (wn + t * 16 + fr) * 32 + fko]);
            }
        #pragma unroll
        for (int kh = 0; kh < 2; ++kh)
            #pragma unroll
            for (int mt = 0; mt < 2; ++mt)
                #pragma unroll
                for (int nt = 0; nt < 2; ++nt)
                    acc[mt][nt] = __builtin_amdgcn_mfma_f32_16x16x32_bf16(
                        af[mt][kh], bfr[nt][kh], acc[mt][nt], 0, 0, 0);

        __syncthreads();
    }

    float* Pp = P + (size_t)blockIdx.z * M * N;
    const int col = lane & 15, qr = (lane >> 4) * 4;
    #pragma unroll
    for (int mt = 0; mt < 2; ++mt)
    #pragma unroll
    for (int nt = 0; nt < 2; ++nt) {
        int gm = m0 + wm + mt * 16 + qr;
        int gn = n0 + wn + nt * 16 + col;
        #pragma unroll
        for (int r = 0; r < 4; ++r)
            Pp[(size_t)(gm + r) * N + gn] = acc[mt][nt][r];
    }
}

// ---- split-K reduce + bias (+relu) epilogue (VERIFIED) ----
template<bool RELU, bool OUTBF16>
__global__ __launch_bounds__(256)
void reduce_ep(const float* __restrict__ P, const float* __restrict__ bias,
               void* __restrict__ Out, int MN, int N, int S)
{
    int e = (blockIdx.x * 256 + threadIdx.x) * 4;
    if (e >= MN) return;
    f32x4 v = *(const f32x4*)(P + e);
    for (int s = 1; s < S; ++s) v += *(const f32x4*)(P + (size_t)s * MN + e);
    int nb = e % N;
    f32x4 bv = *(const f32x4*)(bias + nb);
    v += bv;
    if (RELU) {
        #pragma unroll
        for (int j = 0; j < 4; ++j) v[j] = fmaxf(v[j], 0.f);
    }
    if (OUTBF16) {
        union { unsigned short h[4]; uint2 u; } cv;
        #pragma unroll
        for (int j = 0; j < 4; ++j) cv.h[j] = f2bf(v[j]);
        *(uint2*)((unsigned short*)Out + e) = cv.u;
    } else {
        *(f32x4*)((float*)Out + e) = v;
    }
}

extern "C" void kernel_launch(void* const* d_in, const int* in_sizes, int n_in,
                              void* d_out, int out_size, void* d_ws, size_t ws_size,
                              hipStream_t stream)
{
    const float* x  = (const float*)d_in[0];
    const int*   ei = (const int*)d_in[1];
    const float* gw = (const float*)d_in[2];
    const float* gb = (const float*)d_in[3];
    const float* W1 = (const float*)d_in[4];
    const float* b1 = (const float*)d_in[5];
    const float* W2 = (const float*)d_in[6];
    const float* b2 = (const float*)d_in[7];
    const float* W3 = (const float*)d_in[8];
    const float* b3 = (const float*)d_in[9];
    float* out = (float*)d_out;

    char* ws = (char*)d_ws;
    unsigned short* z   = (unsigned short*)(ws);               // 6,291,456 B
    unsigned short* z1  = (unsigned short*)(ws + 6291456);     // 2,097,152 B
    unsigned short* z2  = (unsigned short*)(ws + 8388608);     // 2,097,152 B
    unsigned short* W1t = (unsigned short*)(ws + 10485760);    // 25,165,824 B
    unsigned short* W2t = (unsigned short*)(ws + 35651584);    // 8,388,608 B
    unsigned short* W3t = (unsigned short*)(ws + 44040192);    // 16,777,216 B
    float* P            = (float*)        (ws + 60817408);     // 33,554,432 B
    int*   c1           = (int*)          (ws + 94371840);
    float* Sg           = (float*)        (ws + 94388224);

    // GCN prologue (small serial chain; atomics isolated in standalone kernels)
    hipLaunchKernelGGL(gcn_init,    dim3(16),  dim3(256), 0, stream, c1, Sg);
    hipLaunchKernelGGL(gcn_hist,    dim3(128), dim3(256), 0, stream, ei + EEDGES, c1);
    hipLaunchKernelGGL(gcn_scatter, dim3(128), dim3(256), 0, stream, ei, ei + EEDGES, x, c1, Sg);

    // build_z (12288 blocks) co-scheduled with W1 transpose (3072 tiles)
    hipLaunchKernelGGL(bz_tcvt1, dim3(15360), dim3(256), 0, stream,
                       x, c1, Sg, gw, gb, z, W1, W1t);

    // L1 GEMM 64x128 (1024 blocks = 4/CU, dispatched first) + W2/W3 transpose in slack
    hipLaunchKernelGGL(gemmL1_tcvt23, dim3(4096), dim3(256), 0, stream,
                       z, W1t, P, W2, W2t, W3, W3t);
    hipLaunchKernelGGL((reduce_ep<true, true>),  dim3(1024), dim3(256), 0, stream, P, b1, (void*)z1, 512 * 2048, 2048, 8);

    // L2: z1[512,2048] @ W2 -> z2 (relu, bf16). 64^2 tile, S=2, chunk 1024, 512 blocks
    hipLaunchKernelGGL(gemm64, dim3(8, 32, 2), dim3(256), 0, stream, z1, W2t, P, 512, 2048, 2048, 1024);
    hipLaunchKernelGGL((reduce_ep<true, true>),  dim3(1024), dim3(256), 0, stream, P, b2, (void*)z2, 512 * 2048, 2048, 2);

    // L3: z2[512,2048] @ W3 -> out (f32). 64x128 tile, S=4, chunk 512, 1024 blocks = 4/CU
    hipLaunchKernelGGL(gemm64x128, dim3(8, 32, 4), dim3(256), 0, stream, z2, W3t, P, 512, 4096, 2048, 512);
    hipLaunchKernelGGL((reduce_ep<false, false>), dim3(2048), dim3(256), 0, stream, P, b3, (void*)out, 512 * 4096, 4096, 4);
}

// Round 13
// 241.352 us; speedup vs baseline: 1.0890x; 1.0890x over previous
//
#include <hip/hip_runtime.h>

#define NEQ_   4096
#define XDIM_  6144
#define EEDGES 32768

typedef __bf16 bf16x8 __attribute__((ext_vector_type(8)));
typedef float  f32x4  __attribute__((ext_vector_type(4)));

__device__ __forceinline__ unsigned short f2bf(float f) {
    union { float f; unsigned u; } v; v.f = f;
    unsigned r = v.u + 0x7FFFu + ((v.u >> 16) & 1u);   // RNE
    return (unsigned short)(r >> 16);
}

__device__ __forceinline__ void gll16(const void* g, void* l) {
    __builtin_amdgcn_global_load_lds(
        (const __attribute__((address_space(1))) unsigned int*)g,
        (__attribute__((address_space(3))) unsigned int*)l, 16, 0, 0);
}

// ---- v4 tcvt tile body (VERIFIED): one 64k x 64n tile, W[K][N] f32 -> Wt[N][K] bf16.
__device__ __forceinline__ void tcvt_tile(const float* __restrict__ W,
                                          unsigned short* __restrict__ Wt,
                                          int K, int N, int kb, int nb,
                                          unsigned int* T, int t)
{
    const int q = t >> 4, i4 = t & 15;
    const float* Wp = W + (size_t)kb * N + nb + i4 * 4;
    f32x4 f[4];
    #pragma unroll
    for (int r = 0; r < 2; ++r)
        #pragma unroll
        for (int p = 0; p < 2; ++p)
            f[r * 2 + p] = *(const f32x4*)(Wp + (size_t)(2 * q + 32 * r + p) * N);

    #pragma unroll
    for (int r = 0; r < 2; ++r)
        #pragma unroll
        for (int j = 0; j < 4; ++j) {
            unsigned lo = f2bf(f[2 * r][j]);
            unsigned hi = f2bf(f[2 * r + 1][j]);
            T[(4 * i4 + j) * 33 + q + 16 * r] = lo | (hi << 16);
        }
    __syncthreads();

    const int rn = t >> 2, c4 = t & 3;
    union { unsigned u[8]; uint4 v[2]; } o;
    #pragma unroll
    for (int s = 0; s < 2; ++s)
        #pragma unroll
        for (int j = 0; j < 4; ++j)
            o.u[s * 4 + j] = T[rn * 33 + 16 * s + 4 * c4 + j];
    unsigned short* dst = Wt + (size_t)(nb + rn) * K + kb + 8 * c4;
    *(uint4*)(dst)      = o.v[0];
    *(uint4*)(dst + 32) = o.v[1];
}

// ---- GCN prologue (small, serial, atomics kept in standalone kernels) ----

__global__ void gcn_init(int* __restrict__ c1, float* __restrict__ S) {
    int i = blockIdx.x * 256 + threadIdx.x;
    if (i < NEQ_) { c1[i] = 0; S[i] = 0.f; }
}

__global__ void gcn_hist(const int* __restrict__ dst, int* __restrict__ c1) {
    int e = blockIdx.x * 256 + threadIdx.x;
    if (e < EEDGES) atomicAdd(&c1[dst[e]], 1);
}

__global__ void gcn_scatter(const int* __restrict__ src, const int* __restrict__ dst,
                            const float* __restrict__ x, const int* __restrict__ c1,
                            float* __restrict__ S) {
    int e = blockIdx.x * 256 + threadIdx.x;
    if (e < EEDGES) {
        int s = src[e], d = dst[e];
        float xf = x[(size_t)(s & 511) * XDIM_ + (s >> 9)];
        float ds = rsqrtf(512.f * (float)c1[s] + 1.f);
        atomicAdd(&S[d], ds * xf);
    }
}

// ---- build_z (12288 blocks) + W1 transpose (3072 tiles) in one grid (VERIFIED r11) ----
__global__ __launch_bounds__(256)
void bz_tcvt1(const float* __restrict__ x, const int* __restrict__ c1,
              const float* __restrict__ S,
              const float* __restrict__ gw, const float* __restrict__ gb,
              unsigned short* __restrict__ z,
              const float* __restrict__ W1, unsigned short* __restrict__ W1t)
{
    __shared__ unsigned int T[64 * 33];   // 8448 B (tcvt branch only)
    const int bid = blockIdx.x, t = threadIdx.x;
    if (bid < 12288) {
        int i = (bid % 24) * 256 + t;
        int b = bid / 24;
        float xv = x[(size_t)b * XDIM_ + i];
        float v;
        if (i >= NEQ_) {
            v = xv;
        } else {
            float w00 = gw[0], b0 = gb[0];
            if (i >= 8) {
                v = fmaxf(w00 * xv + b0, 0.f);
            } else {
                int n = i * 512 + b;
                float deg = 512.f * (float)c1[n] + 1.f;
                float dn = rsqrtf(deg);
                float outv = w00 * (512.f * dn * S[n] + xv / deg);
                v = fmaxf(outv + b0, 0.f);
            }
        }
        z[(size_t)b * XDIM_ + i] = f2bf(v);
        return;
    }
    int b2 = bid - 12288;
    tcvt_tile(W1, W1t, 6144, 2048, (b2 % 96) * 64, (b2 / 96) * 64, T, t);
}

// ---- L1 GEMM 128x128 (512 blocks, bid<512 dispatch first) + W2/W3 transpose
// (3072 tiles) in CU slack. r13: XCD-bijective swizzle sw=(bid&7)*64+(bid>>3)
// so XCD x (round-robin bid%8==x) owns split-K slice x entirely -> slice
// working set (W1t 3MB + z 0.75MB) fits the XCD's private 4MB L2.
// (r12 lesson: 64x128 tile halves B-reuse -> FETCH +46MB, HBM-bound; 128^2 kept.)
__global__ __launch_bounds__(256)
void gemmL1_tcvt23(const unsigned short* __restrict__ A,   // z [512][6144]
                   const unsigned short* __restrict__ Bt,  // W1t [2048][6144]
                   float* __restrict__ P,                   // [8][512][2048]
                   const float* __restrict__ W2, unsigned short* __restrict__ W2t,
                   const float* __restrict__ W3, unsigned short* __restrict__ W3t)
{
    __shared__ unsigned short As[2 * 128 * 32];  // 16 KB
    __shared__ unsigned short Bs[2 * 128 * 32];  // 16 KB
    const int bid = blockIdx.x;
    if (bid >= 512) {
        // W2: 1024 tiles (32x32), W3: 2048 tiles (32x64); K=2048
        unsigned int* T = (unsigned int*)As;     // reuse 8.4 KB of As
        int b2 = bid - 512;
        if (b2 < 1024)
            tcvt_tile(W2, W2t, 2048, 2048, (b2 % 32) * 64, (b2 / 32) * 64, T, threadIdx.x);
        else {
            int b3 = b2 - 1024;
            tcvt_tile(W3, W3t, 2048, 4096, (b3 % 32) * 64, (b3 / 32) * 64, T, threadIdx.x);
        }
        return;
    }
    constexpr int K = 6144, N = 2048, KCHUNK = 768;
    const int sw = ((bid & 7) << 6) | (bid >> 3);   // bijective on [0,512)
    const int tid = threadIdx.x, lane = tid & 63, wave = tid >> 6;
    const int m0 = (sw & 3) * 128, n0 = ((sw >> 2) & 15) * 128;
    const int sidx = sw >> 6;
    const int wm = (wave >> 1) * 64, wn = (wave & 1) * 64;
    const int fr = lane & 15, fko = (lane >> 4) * 8;
    const int k0 = sidx * KCHUNK, k1 = k0 + KCHUNK;

    const int srow = tid >> 2;
    const int sko  = (tid & 3) * 8;
    const size_t aoff0 = (size_t)(m0 + srow) * K + sko;
    const size_t aoff1 = (size_t)(m0 + 64 + srow) * K + sko;
    const size_t boff0 = (size_t)(n0 + srow) * K + sko;
    const size_t boff1 = (size_t)(n0 + 64 + srow) * K + sko;
    unsigned short* asl = &As[srow * 32 + sko];
    unsigned short* bsl = &Bs[srow * 32 + sko];

    f32x4 acc[4][4] = {};

    for (int kk = k0; kk < k1; kk += 64) {
        gll16(A + aoff0 + kk,      asl);
        gll16(A + aoff1 + kk,      asl + 2048);
        gll16(A + aoff0 + kk + 32, asl + 4096);
        gll16(A + aoff1 + kk + 32, asl + 6144);
        gll16(Bt + boff0 + kk,      bsl);
        gll16(Bt + boff1 + kk,      bsl + 2048);
        gll16(Bt + boff0 + kk + 32, bsl + 4096);
        gll16(Bt + boff1 + kk + 32, bsl + 6144);
        __syncthreads();

        bf16x8 af[4][2], bfr[4][2];
        #pragma unroll
        for (int kh = 0; kh < 2; ++kh)
            #pragma unroll
            for (int t = 0; t < 4; ++t) {
                af[t][kh]  = *(const bf16x8*)(&As[kh * 4096 + (wm + t * 16 + fr) * 32 + fko]);
                bfr[t][kh] = *(const bf16x8*)(&Bs[kh * 4096 + (wn + t * 16 + fr) * 32 + fko]);
            }
        #pragma unroll
        for (int kh = 0; kh < 2; ++kh)
            #pragma unroll
            for (int mt = 0; mt < 4; ++mt)
                #pragma unroll
                for (int nt = 0; nt < 4; ++nt)
                    acc[mt][nt] = __builtin_amdgcn_mfma_f32_16x16x32_bf16(
                        af[mt][kh], bfr[nt][kh], acc[mt][nt], 0, 0, 0);

        __syncthreads();
    }

    float* Pp = P + (size_t)sidx * 512 * N;
    const int col = lane & 15, qr = (lane >> 4) * 4;
    #pragma unroll
    for (int mt = 0; mt < 4; ++mt)
    #pragma unroll
    for (int nt = 0; nt < 4; ++nt) {
        int gm = m0 + wm + mt * 16 + qr;
        int gn = n0 + wn + nt * 16 + col;
        #pragma unroll
        for (int r = 0; r < 4; ++r)
            Pp[(size_t)(gm + r) * N + gn] = acc[mt][nt][r];
    }
}

// ---- L3 GEMM: 128x128 tile, 1-D grid of 512 with XCD-bijective swizzle.
// M=512 N=4096 K=2048 KCHUNK=512 (S=4). Per-XCD working set: 16 n-tiles of
// W3t (2MB) + z2 k-chunk (0.5MB) = 2.5MB < 4MB L2. Body = VERIFIED gemm128. ----
__global__ __launch_bounds__(256)
void gemm128_L3(const unsigned short* __restrict__ A,   // z2 [512][2048]
                const unsigned short* __restrict__ Bt,  // W3t [4096][2048]
                float* __restrict__ P)                  // [4][512][4096]
{
    __shared__ unsigned short As[2 * 128 * 32];  // 16 KB
    __shared__ unsigned short Bs[2 * 128 * 32];  // 16 KB
    const int K = 2048, N = 4096, KCHUNK = 512;
    const int bid = blockIdx.x;
    const int sw = ((bid & 7) << 6) | (bid >> 3);   // bijective on [0,512)
    const int tid = threadIdx.x, lane = tid & 63, wave = tid >> 6;
    const int tt = sw & 127;
    const int m0 = (tt & 3) * 128, n0 = (tt >> 2) * 128;   // 4 m x 32 n tiles
    const int sidx = sw >> 7;                               // 4 slices
    const int wm = (wave >> 1) * 64, wn = (wave & 1) * 64;
    const int fr = lane & 15, fko = (lane >> 4) * 8;
    const int k0 = sidx * KCHUNK, k1 = k0 + KCHUNK;

    const int srow = tid >> 2;
    const int sko  = (tid & 3) * 8;
    const size_t aoff0 = (size_t)(m0 + srow) * K + sko;
    const size_t aoff1 = (size_t)(m0 + 64 + srow) * K + sko;
    const size_t boff0 = (size_t)(n0 + srow) * K + sko;
    const size_t boff1 = (size_t)(n0 + 64 + srow) * K + sko;
    unsigned short* asl = &As[srow * 32 + sko];
    unsigned short* bsl = &Bs[srow * 32 + sko];

    f32x4 acc[4][4] = {};

    for (int kk = k0; kk < k1; kk += 64) {
        gll16(A + aoff0 + kk,      asl);
        gll16(A + aoff1 + kk,      asl + 2048);
        gll16(A + aoff0 + kk + 32, asl + 4096);
        gll16(A + aoff1 + kk + 32, asl + 6144);
        gll16(Bt + boff0 + kk,      bsl);
        gll16(Bt + boff1 + kk,      bsl + 2048);
        gll16(Bt + boff0 + kk + 32, bsl + 4096);
        gll16(Bt + boff1 + kk + 32, bsl + 6144);
        __syncthreads();

        bf16x8 af[4][2], bfr[4][2];
        #pragma unroll
        for (int kh = 0; kh < 2; ++kh)
            #pragma unroll
            for (int t = 0; t < 4; ++t) {
                af[t][kh]  = *(const bf16x8*)(&As[kh * 4096 + (wm + t * 16 + fr) * 32 + fko]);
                bfr[t][kh] = *(const bf16x8*)(&Bs[kh * 4096 + (wn + t * 16 + fr) * 32 + fko]);
            }
        #pragma unroll
        for (int kh = 0; kh < 2; ++kh)
            #pragma unroll
            for (int mt = 0; mt < 4; ++mt)
                #pragma unroll
                for (int nt = 0; nt < 4; ++nt)
                    acc[mt][nt] = __builtin_amdgcn_mfma_f32_16x16x32_bf16(
                        af[mt][kh], bfr[nt][kh], acc[mt][nt], 0, 0, 0);

        __syncthreads();
    }

    float* Pp = P + (size_t)sidx * 512 * N;
    const int col = lane & 15, qr = (lane >> 4) * 4;
    #pragma unroll
    for (int mt = 0; mt < 4; ++mt)
    #pragma unroll
    for (int nt = 0; nt < 4; ++nt) {
        int gm = m0 + wm + mt * 16 + qr;
        int gn = n0 + wn + nt * 16 + col;
        #pragma unroll
        for (int r = 0; r < 4; ++r)
            Pp[(size_t)(gm + r) * N + gn] = acc[mt][nt][r];
    }
}

// ---- 64x64-tile MFMA GEMM (VERIFIED; L2) ----
__global__ __launch_bounds__(256)
void gemm64(const unsigned short* __restrict__ A,   // [M][K] bf16
            const unsigned short* __restrict__ Bt,  // [N][K] bf16
            float* __restrict__ P,                  // [S][M][N] f32
            int M, int N, int K, int kChunk)
{
    __shared__ unsigned short As[2 * 64 * 32];   // 8 KB
    __shared__ unsigned short Bs[2 * 64 * 32];   // 8 KB
    const int tid = threadIdx.x, lane = tid & 63, wave = tid >> 6;
    const int m0 = blockIdx.x * 64, n0 = blockIdx.y * 64;
    const int wm = (wave >> 1) * 32, wn = (wave & 1) * 32;
    const int fr = lane & 15, fko = (lane >> 4) * 8;
    const int k0 = blockIdx.z * kChunk, k1 = k0 + kChunk;

    const int srow = tid >> 2;
    const int sko  = (tid & 3) * 8;
    const size_t aoff = (size_t)(m0 + srow) * K + sko;
    const size_t boff = (size_t)(n0 + srow) * K + sko;
    unsigned short* asl0 = &As[srow * 32 + sko];
    unsigned short* asl1 = &As[2048 + srow * 32 + sko];
    unsigned short* bsl0 = &Bs[srow * 32 + sko];
    unsigned short* bsl1 = &Bs[2048 + srow * 32 + sko];

    f32x4 acc[2][2] = {};

    for (int kk = k0; kk < k1; kk += 64) {
        gll16(A + aoff + kk,      asl0);
        gll16(A + aoff + kk + 32, asl1);
        gll16(Bt + boff + kk,      bsl0);
        gll16(Bt + boff + kk + 32, bsl1);
        __syncthreads();

        bf16x8 af[2][2], bfr[2][2];
        #pragma unroll
        for (int kh = 0; kh < 2; ++kh)
            #pragma unroll
            for (int t = 0; t < 2; ++t) {
                af[t][kh]  = *(const bf16x8*)(&As[kh * 2048 + (wm + t * 16 + fr) * 32 + fko]);
                bfr[t][kh] = *(const bf16x8*)(&Bs[kh * 2048 + (wn + t * 16 + fr) * 32 + fko]);
            }
        #pragma unroll
        for (int kh = 0; kh < 2; ++kh)
            #pragma unroll
            for (int mt = 0; mt < 2; ++mt)
                #pragma unroll
                for (int nt = 0; nt < 2; ++nt)
                    acc[mt][nt] = __builtin_amdgcn_mfma_f32_16x16x32_bf16(
                        af[mt][kh], bfr[nt][kh], acc[mt][nt], 0, 0, 0);

        __syncthreads();
    }

    float* Pp = P + (size_t)blockIdx.z * M * N;
    const int col = lane & 15, qr = (lane >> 4) * 4;
    #pragma unroll
    for (int mt = 0; mt < 2; ++mt)
    #pragma unroll
    for (int nt = 0; nt < 2; ++nt) {
        int gm = m0 + wm + mt * 16 + qr;
        int gn = n0 + wn + nt * 16 + col;
        #pragma unroll
        for (int r = 0; r < 4; ++r)
            Pp[(size_t)(gm + r) * N + gn] = acc[mt][nt][r];
    }
}

// ---- split-K reduce + bias (+relu) epilogue (VERIFIED) ----
template<bool RELU, bool OUTBF16>
__global__ __launch_bounds__(256)
void reduce_ep(const float* __restrict__ P, const float* __restrict__ bias,
               void* __restrict__ Out, int MN, int N, int S)
{
    int e = (blockIdx.x * 256 + threadIdx.x) * 4;
    if (e >= MN) return;
    f32x4 v = *(const f32x4*)(P + e);
    for (int s = 1; s < S; ++s) v += *(const f32x4*)(P + (size_t)s * MN + e);
    int nb = e % N;
    f32x4 bv = *(const f32x4*)(bias + nb);
    v += bv;
    if (RELU) {
        #pragma unroll
        for (int j = 0; j < 4; ++j) v[j] = fmaxf(v[j], 0.f);
    }
    if (OUTBF16) {
        union { unsigned short h[4]; uint2 u; } cv;
        #pragma unroll
        for (int j = 0; j < 4; ++j) cv.h[j] = f2bf(v[j]);
        *(uint2*)((unsigned short*)Out + e) = cv.u;
    } else {
        *(f32x4*)((float*)Out + e) = v;
    }
}

extern "C" void kernel_launch(void* const* d_in, const int* in_sizes, int n_in,
                              void* d_out, int out_size, void* d_ws, size_t ws_size,
                              hipStream_t stream)
{
    const float* x  = (const float*)d_in[0];
    const int*   ei = (const int*)d_in[1];
    const float* gw = (const float*)d_in[2];
    const float* gb = (const float*)d_in[3];
    const float* W1 = (const float*)d_in[4];
    const float* b1 = (const float*)d_in[5];
    const float* W2 = (const float*)d_in[6];
    const float* b2 = (const float*)d_in[7];
    const float* W3 = (const float*)d_in[8];
    const float* b3 = (const float*)d_in[9];
    float* out = (float*)d_out;

    char* ws = (char*)d_ws;
    unsigned short* z   = (unsigned short*)(ws);               // 6,291,456 B
    unsigned short* z1  = (unsigned short*)(ws + 6291456);     // 2,097,152 B
    unsigned short* z2  = (unsigned short*)(ws + 8388608);     // 2,097,152 B
    unsigned short* W1t = (unsigned short*)(ws + 10485760);    // 25,165,824 B
    unsigned short* W2t = (unsigned short*)(ws + 35651584);    // 8,388,608 B
    unsigned short* W3t = (unsigned short*)(ws + 44040192);    // 16,777,216 B
    float* P            = (float*)        (ws + 60817408);     // 33,554,432 B
    int*   c1           = (int*)          (ws + 94371840);
    float* Sg           = (float*)        (ws + 94388224);

    // GCN prologue (small serial chain; atomics isolated in standalone kernels)
    hipLaunchKernelGGL(gcn_init,    dim3(16),  dim3(256), 0, stream, c1, Sg);
    hipLaunchKernelGGL(gcn_hist,    dim3(128), dim3(256), 0, stream, ei + EEDGES, c1);
    hipLaunchKernelGGL(gcn_scatter, dim3(128), dim3(256), 0, stream, ei, ei + EEDGES, x, c1, Sg);

    // build_z (12288 blocks) co-scheduled with W1 transpose (3072 tiles)
    hipLaunchKernelGGL(bz_tcvt1, dim3(15360), dim3(256), 0, stream,
                       x, c1, Sg, gw, gb, z, W1, W1t);

    // L1 GEMM 128x128 XCD-swizzled (512 blocks first) + W2/W3 transpose in slack
    hipLaunchKernelGGL(gemmL1_tcvt23, dim3(3584), dim3(256), 0, stream,
                       z, W1t, P, W2, W2t, W3, W3t);
    hipLaunchKernelGGL((reduce_ep<true, true>),  dim3(1024), dim3(256), 0, stream, P, b1, (void*)z1, 512 * 2048, 2048, 8);

    // L2: z1[512,2048] @ W2 -> z2 (relu, bf16). 64^2 tile, S=2, chunk 1024, 512 blocks
    hipLaunchKernelGGL(gemm64, dim3(8, 32, 2), dim3(256), 0, stream, z1, W2t, P, 512, 2048, 2048, 1024);
    hipLaunchKernelGGL((reduce_ep<true, true>),  dim3(1024), dim3(256), 0, stream, P, b2, (void*)z2, 512 * 2048, 2048, 2);

    // L3: z2[512,2048] @ W3 -> out (f32). 128^2 tile XCD-swizzled, S=4, 512 blocks
    hipLaunchKernelGGL(gemm128_L3, dim3(512), dim3(256), 0, stream, z2, W3t, P);
    hipLaunchKernelGGL((reduce_ep<false, false>), dim3(2048), dim3(256), 0, stream, P, b3, (void*)out, 512 * 4096, 4096, 4);
}

// Round 14
// 239.743 us; speedup vs baseline: 1.0963x; 1.0067x over previous
//
#include <hip/hip_runtime.h>

#define NEQ_   4096
#define XDIM_  6144
#define EEDGES 32768

typedef __bf16 bf16x8 __attribute__((ext_vector_type(8)));
typedef float  f32x4  __attribute__((ext_vector_type(4)));

__device__ __forceinline__ unsigned short f2bf(float f) {
    union { float f; unsigned u; } v; v.f = f;
    unsigned r = v.u + 0x7FFFu + ((v.u >> 16) & 1u);   // RNE
    return (unsigned short)(r >> 16);
}

__device__ __forceinline__ void gll16(const void* g, void* l) {
    __builtin_amdgcn_global_load_lds(
        (const __attribute__((address_space(1))) unsigned int*)g,
        (__attribute__((address_space(3))) unsigned int*)l, 16, 0, 0);
}

// ---- v4 tcvt tile body (VERIFIED): one 64k x 64n tile, W[K][N] f32 -> Wt[N][K] bf16.
__device__ __forceinline__ void tcvt_tile(const float* __restrict__ W,
                                          unsigned short* __restrict__ Wt,
                                          int K, int N, int kb, int nb,
                                          unsigned int* T, int t)
{
    const int q = t >> 4, i4 = t & 15;
    const float* Wp = W + (size_t)kb * N + nb + i4 * 4;
    f32x4 f[4];
    #pragma unroll
    for (int r = 0; r < 2; ++r)
        #pragma unroll
        for (int p = 0; p < 2; ++p)
            f[r * 2 + p] = *(const f32x4*)(Wp + (size_t)(2 * q + 32 * r + p) * N);

    #pragma unroll
    for (int r = 0; r < 2; ++r)
        #pragma unroll
        for (int j = 0; j < 4; ++j) {
            unsigned lo = f2bf(f[2 * r][j]);
            unsigned hi = f2bf(f[2 * r + 1][j]);
            T[(4 * i4 + j) * 33 + q + 16 * r] = lo | (hi << 16);
        }
    __syncthreads();

    const int rn = t >> 2, c4 = t & 3;
    union { unsigned u[8]; uint4 v[2]; } o;
    #pragma unroll
    for (int s = 0; s < 2; ++s)
        #pragma unroll
        for (int j = 0; j < 4; ++j)
            o.u[s * 4 + j] = T[rn * 33 + 16 * s + 4 * c4 + j];
    unsigned short* dst = Wt + (size_t)(nb + rn) * K + kb + 8 * c4;
    *(uint4*)(dst)      = o.v[0];
    *(uint4*)(dst + 32) = o.v[1];
}

// ---- GCN prologue (small, serial, atomics kept in standalone kernels) ----

__global__ void gcn_init(int* __restrict__ c1, float* __restrict__ S) {
    int i = blockIdx.x * 256 + threadIdx.x;
    if (i < NEQ_) { c1[i] = 0; S[i] = 0.f; }
}

__global__ void gcn_hist(const int* __restrict__ dst, int* __restrict__ c1) {
    int e = blockIdx.x * 256 + threadIdx.x;
    if (e < EEDGES) atomicAdd(&c1[dst[e]], 1);
}

__global__ void gcn_scatter(const int* __restrict__ src, const int* __restrict__ dst,
                            const float* __restrict__ x, const int* __restrict__ c1,
                            float* __restrict__ S) {
    int e = blockIdx.x * 256 + threadIdx.x;
    if (e < EEDGES) {
        int s = src[e], d = dst[e];
        float xf = x[(size_t)(s & 511) * XDIM_ + (s >> 9)];
        float ds = rsqrtf(512.f * (float)c1[s] + 1.f);
        atomicAdd(&S[d], ds * xf);
    }
}

// ---- build_z (12288 blocks) + W1 transpose (3072 tiles) in one grid (VERIFIED r11) ----
__global__ __launch_bounds__(256)
void bz_tcvt1(const float* __restrict__ x, const int* __restrict__ c1,
              const float* __restrict__ S,
              const float* __restrict__ gw, const float* __restrict__ gb,
              unsigned short* __restrict__ z,
              const float* __restrict__ W1, unsigned short* __restrict__ W1t)
{
    __shared__ unsigned int T[64 * 33];   // 8448 B (tcvt branch only)
    const int bid = blockIdx.x, t = threadIdx.x;
    if (bid < 12288) {
        int i = (bid % 24) * 256 + t;
        int b = bid / 24;
        float xv = x[(size_t)b * XDIM_ + i];
        float v;
        if (i >= NEQ_) {
            v = xv;
        } else {
            float w00 = gw[0], b0 = gb[0];
            if (i >= 8) {
                v = fmaxf(w00 * xv + b0, 0.f);
            } else {
                int n = i * 512 + b;
                float deg = 512.f * (float)c1[n] + 1.f;
                float dn = rsqrtf(deg);
                float outv = w00 * (512.f * dn * S[n] + xv / deg);
                v = fmaxf(outv + b0, 0.f);
            }
        }
        z[(size_t)b * XDIM_ + i] = f2bf(v);
        return;
    }
    int b2 = bid - 12288;
    tcvt_tile(W1, W1t, 6144, 2048, (b2 % 96) * 64, (b2 / 96) * 64, T, t);
}

// ---- L1 GEMM 64m x 128n (1024 blocks = 4/CU) with slice-per-XCD swizzle
// + W2/W3 transpose (3072 tiles) in CU slack.
// r14 = r12's occupancy (4/CU, verified-correct 64x128 body) + r13's locality
// (XCD x = bid%8 owns split-K slice x; slice set = W1t 3MB + z 0.75MB < 4MB L2,
// so the 8 m-blocks' B-panel re-reads are L2 hits, not HBM -- fixing r12's
// 126MB FETCH). Within an XCD, 8 consecutive-m blocks share each 192KB B-panel.
__global__ __launch_bounds__(256)
void gemmL1_tcvt23(const unsigned short* __restrict__ A,   // z [512][6144]
                   const unsigned short* __restrict__ Bt,  // W1t [2048][6144]
                   float* __restrict__ P,                   // [8][512][2048]
                   const float* __restrict__ W2, unsigned short* __restrict__ W2t,
                   const float* __restrict__ W3, unsigned short* __restrict__ W3t)
{
    __shared__ unsigned short As[2 * 64 * 32];   // 8 KB
    __shared__ unsigned short Bs[2 * 128 * 32];  // 16 KB
    const int bid = blockIdx.x;
    if (bid >= 1024) {
        unsigned int* T = (unsigned int*)Bs;     // 8448 B <= 16 KB
        int b2 = bid - 1024;
        if (b2 < 1024)
            tcvt_tile(W2, W2t, 2048, 2048, (b2 % 32) * 64, (b2 / 32) * 64, T, threadIdx.x);
        else {
            int b3 = b2 - 1024;
            tcvt_tile(W3, W3t, 2048, 4096, (b3 % 32) * 64, (b3 / 32) * 64, T, threadIdx.x);
        }
        return;
    }
    constexpr int K = 6144, N = 2048, KCHUNK = 768;
    // bijective: XCD (bid&7) owns slice (bid&7); t = bid>>3 walks m fastest
    const int sidx = bid & 7;                    // 8 split-K slices, 1 per XCD
    const int tt   = bid >> 3;                   // 0..127 within slice
    const int m0 = (tt & 7) * 64;                // 8 m-tiles (fastest -> B-panel reuse)
    const int n0 = (tt >> 3) * 128;              // 16 n-tiles
    const int tid = threadIdx.x, lane = tid & 63, wave = tid >> 6;
    const int wm = (wave >> 1) * 32, wn = (wave & 1) * 64;
    const int fr = lane & 15, fko = (lane >> 4) * 8;
    const int k0 = sidx * KCHUNK, k1 = k0 + KCHUNK;

    const int srow = tid >> 2;
    const int sko  = (tid & 3) * 8;
    const size_t aoff  = (size_t)(m0 + srow) * K + sko;
    const size_t boff0 = (size_t)(n0 + srow) * K + sko;
    const size_t boff1 = (size_t)(n0 + 64 + srow) * K + sko;
    unsigned short* asl = &As[srow * 32 + sko];
    unsigned short* bsl = &Bs[srow * 32 + sko];

    f32x4 acc[2][4] = {};

    for (int kk = k0; kk < k1; kk += 64) {
        gll16(A + aoff + kk,        asl);
        gll16(A + aoff + kk + 32,   asl + 2048);
        gll16(Bt + boff0 + kk,      bsl);
        gll16(Bt + boff1 + kk,      bsl + 2048);
        gll16(Bt + boff0 + kk + 32, bsl + 4096);
        gll16(Bt + boff1 + kk + 32, bsl + 6144);
        __syncthreads();

        bf16x8 af[2][2], bfr[4][2];
        #pragma unroll
        for (int kh = 0; kh < 2; ++kh) {
            #pragma unroll
            for (int t = 0; t < 2; ++t)
                af[t][kh]  = *(const bf16x8*)(&As[kh * 2048 + (wm + t * 16 + fr) * 32 + fko]);
            #pragma unroll
            for (int u = 0; u < 4; ++u)
                bfr[u][kh] = *(const bf16x8*)(&Bs[kh * 4096 + (wn + u * 16 + fr) * 32 + fko]);
        }
        #pragma unroll
        for (int kh = 0; kh < 2; ++kh)
            #pragma unroll
            for (int mt = 0; mt < 2; ++mt)
                #pragma unroll
                for (int nt = 0; nt < 4; ++nt)
                    acc[mt][nt] = __builtin_amdgcn_mfma_f32_16x16x32_bf16(
                        af[mt][kh], bfr[nt][kh], acc[mt][nt], 0, 0, 0);

        __syncthreads();
    }

    float* Pp = P + (size_t)sidx * 512 * N;
    const int col = lane & 15, qr = (lane >> 4) * 4;
    #pragma unroll
    for (int mt = 0; mt < 2; ++mt)
    #pragma unroll
    for (int nt = 0; nt < 4; ++nt) {
        int gm = m0 + wm + mt * 16 + qr;
        int gn = n0 + wn + nt * 16 + col;
        #pragma unroll
        for (int r = 0; r < 4; ++r)
            Pp[(size_t)(gm + r) * N + gn] = acc[mt][nt][r];
    }
}

// ---- L3 GEMM 64m x 128n (1024 blocks = 4/CU), slice per XCD-pair.
// M=512 N=4096 K=2048 KCHUNK=512 S=4. Per-XCD set: 16 n-tiles W3t (2MB) +
// z2 chunk (0.5MB) < 4MB L2. Body = r12-verified 64x128. ----
__global__ __launch_bounds__(256)
void gemm_L3(const unsigned short* __restrict__ A,   // z2 [512][2048]
             const unsigned short* __restrict__ Bt,  // W3t [4096][2048]
             float* __restrict__ P)                  // [4][512][4096]
{
    __shared__ unsigned short As[2 * 64 * 32];   // 8 KB
    __shared__ unsigned short Bs[2 * 128 * 32];  // 16 KB
    constexpr int K = 2048, N = 4096, KCHUNK = 512;
    const int bid = blockIdx.x;
    const int xcd = bid & 7;
    const int sidx = xcd >> 1;                   // slice per XCD-pair
    // within slice: 256 blocks = 2 XCDs x 128; n split across the pair
    const int tt = (bid >> 3) | ((xcd & 1) << 7);   // 0..255
    const int m0 = (tt & 7) * 64;                // 8 m-tiles fastest
    const int n0 = (tt >> 3) * 128;              // 32 n-tiles
    const int tid = threadIdx.x, lane = tid & 63, wave = tid >> 6;
    const int wm = (wave >> 1) * 32, wn = (wave & 1) * 64;
    const int fr = lane & 15, fko = (lane >> 4) * 8;
    const int k0 = sidx * KCHUNK, k1 = k0 + KCHUNK;

    const int srow = tid >> 2;
    const int sko  = (tid & 3) * 8;
    const size_t aoff  = (size_t)(m0 + srow) * K + sko;
    const size_t boff0 = (size_t)(n0 + srow) * K + sko;
    const size_t boff1 = (size_t)(n0 + 64 + srow) * K + sko;
    unsigned short* asl = &As[srow * 32 + sko];
    unsigned short* bsl = &Bs[srow * 32 + sko];

    f32x4 acc[2][4] = {};

    for (int kk = k0; kk < k1; kk += 64) {
        gll16(A + aoff + kk,        asl);
        gll16(A + aoff + kk + 32,   asl + 2048);
        gll16(Bt + boff0 + kk,      bsl);
        gll16(Bt + boff1 + kk,      bsl + 2048);
        gll16(Bt + boff0 + kk + 32, bsl + 4096);
        gll16(Bt + boff1 + kk + 32, bsl + 6144);
        __syncthreads();

        bf16x8 af[2][2], bfr[4][2];
        #pragma unroll
        for (int kh = 0; kh < 2; ++kh) {
            #pragma unroll
            for (int t = 0; t < 2; ++t)
                af[t][kh]  = *(const bf16x8*)(&As[kh * 2048 + (wm + t * 16 + fr) * 32 + fko]);
            #pragma unroll
            for (int u = 0; u < 4; ++u)
                bfr[u][kh] = *(const bf16x8*)(&Bs[kh * 4096 + (wn + u * 16 + fr) * 32 + fko]);
        }
        #pragma unroll
        for (int kh = 0; kh < 2; ++kh)
            #pragma unroll
            for (int mt = 0; mt < 2; ++mt)
                #pragma unroll
                for (int nt = 0; nt < 4; ++nt)
                    acc[mt][nt] = __builtin_amdgcn_mfma_f32_16x16x32_bf16(
                        af[mt][kh], bfr[nt][kh], acc[mt][nt], 0, 0, 0);

        __syncthreads();
    }

    float* Pp = P + (size_t)sidx * 512 * N;
    const int col = lane & 15, qr = (lane >> 4) * 4;
    #pragma unroll
    for (int mt = 0; mt < 2; ++mt)
    #pragma unroll
    for (int nt = 0; nt < 4; ++nt) {
        int gm = m0 + wm + mt * 16 + qr;
        int gn = n0 + wn + nt * 16 + col;
        #pragma unroll
        for (int r = 0; r < 4; ++r)
            Pp[(size_t)(gm + r) * N + gn] = acc[mt][nt][r];
    }
}

// ---- 64x64-tile MFMA GEMM (VERIFIED; L2) ----
__global__ __launch_bounds__(256)
void gemm64(const unsigned short* __restrict__ A,   // [M][K] bf16
            const unsigned short* __restrict__ Bt,  // [N][K] bf16
            float* __restrict__ P,                  // [S][M][N] f32
            int M, int N, int K, int kChunk)
{
    __shared__ unsigned short As[2 * 64 * 32];   // 8 KB
    __shared__ unsigned short Bs[2 * 64 * 32];   // 8 KB
    const int tid = threadIdx.x, lane = tid & 63, wave = tid >> 6;
    const int m0 = blockIdx.x * 64, n0 = blockIdx.y * 64;
    const int wm = (wave >> 1) * 32, wn = (wave & 1) * 32;
    const int fr = lane & 15, fko = (lane >> 4) * 8;
    const int k0 = blockIdx.z * kChunk, k1 = k0 + kChunk;

    const int srow = tid >> 2;
    const int sko  = (tid & 3) * 8;
    const size_t aoff = (size_t)(m0 + srow) * K + sko;
    const size_t boff = (size_t)(n0 + srow) * K + sko;
    unsigned short* asl0 = &As[srow * 32 + sko];
    unsigned short* asl1 = &As[2048 + srow * 32 + sko];
    unsigned short* bsl0 = &Bs[srow * 32 + sko];
    unsigned short* bsl1 = &Bs[2048 + srow * 32 + sko];

    f32x4 acc[2][2] = {};

    for (int kk = k0; kk < k1; kk += 64) {
        gll16(A + aoff + kk,      asl0);
        gll16(A + aoff + kk + 32, asl1);
        gll16(Bt + boff + kk,      bsl0);
        gll16(Bt + boff + kk + 32, bsl1);
        __syncthreads();

        bf16x8 af[2][2], bfr[2][2];
        #pragma unroll
        for (int kh = 0; kh < 2; ++kh)
            #pragma unroll
            for (int t = 0; t < 2; ++t) {
                af[t][kh]  = *(const bf16x8*)(&As[kh * 2048 + (wm + t * 16 + fr) * 32 + fko]);
                bfr[t][kh] = *(const bf16x8*)(&Bs[kh * 2048 + (wn + t * 16 + fr) * 32 + fko]);
            }
        #pragma unroll
        for (int kh = 0; kh < 2; ++kh)
            #pragma unroll
            for (int mt = 0; mt < 2; ++mt)
                #pragma unroll
                for (int nt = 0; nt < 2; ++nt)
                    acc[mt][nt] = __builtin_amdgcn_mfma_f32_16x16x32_bf16(
                        af[mt][kh], bfr[nt][kh], acc[mt][nt], 0, 0, 0);

        __syncthreads();
    }

    float* Pp = P + (size_t)blockIdx.z * M * N;
    const int col = lane & 15, qr = (lane >> 4) * 4;
    #pragma unroll
    for (int mt = 0; mt < 2; ++mt)
    #pragma unroll
    for (int nt = 0; nt < 2; ++nt) {
        int gm = m0 + wm + mt * 16 + qr;
        int gn = n0 + wn + nt * 16 + col;
        #pragma unroll
        for (int r = 0; r < 4; ++r)
            Pp[(size_t)(gm + r) * N + gn] = acc[mt][nt][r];
    }
}

// ---- split-K reduce + bias (+relu) epilogue (VERIFIED) ----
template<bool RELU, bool OUTBF16>
__global__ __launch_bounds__(256)
void reduce_ep(const float* __restrict__ P, const float* __restrict__ bias,
               void* __restrict__ Out, int MN, int N, int S)
{
    int e = (blockIdx.x * 256 + threadIdx.x) * 4;
    if (e >= MN) return;
    f32x4 v = *(const f32x4*)(P + e);
    for (int s = 1; s < S; ++s) v += *(const f32x4*)(P + (size_t)s * MN + e);
    int nb = e % N;
    f32x4 bv = *(const f32x4*)(bias + nb);
    v += bv;
    if (RELU) {
        #pragma unroll
        for (int j = 0; j < 4; ++j) v[j] = fmaxf(v[j], 0.f);
    }
    if (OUTBF16) {
        union { unsigned short h[4]; uint2 u; } cv;
        #pragma unroll
        for (int j = 0; j < 4; ++j) cv.h[j] = f2bf(v[j]);
        *(uint2*)((unsigned short*)Out + e) = cv.u;
    } else {
        *(f32x4*)((float*)Out + e) = v;
    }
}

extern "C" void kernel_launch(void* const* d_in, const int* in_sizes, int n_in,
                              void* d_out, int out_size, void* d_ws, size_t ws_size,
                              hipStream_t stream)
{
    const float* x  = (const float*)d_in[0];
    const int*   ei = (const int*)d_in[1];
    const float* gw = (const float*)d_in[2];
    const float* gb = (const float*)d_in[3];
    const float* W1 = (const float*)d_in[4];
    const float* b1 = (const float*)d_in[5];
    const float* W2 = (const float*)d_in[6];
    const float* b2 = (const float*)d_in[7];
    const float* W3 = (const float*)d_in[8];
    const float* b3 = (const float*)d_in[9];
    float* out = (float*)d_out;

    char* ws = (char*)d_ws;
    unsigned short* z   = (unsigned short*)(ws);               // 6,291,456 B
    unsigned short* z1  = (unsigned short*)(ws + 6291456);     // 2,097,152 B
    unsigned short* z2  = (unsigned short*)(ws + 8388608);     // 2,097,152 B
    unsigned short* W1t = (unsigned short*)(ws + 10485760);    // 25,165,824 B
    unsigned short* W2t = (unsigned short*)(ws + 35651584);    // 8,388,608 B
    unsigned short* W3t = (unsigned short*)(ws + 44040192);    // 16,777,216 B
    float* P            = (float*)        (ws + 60817408);     // 33,554,432 B
    int*   c1           = (int*)          (ws + 94371840);
    float* Sg           = (float*)        (ws + 94388224);

    // GCN prologue (small serial chain; atomics isolated in standalone kernels)
    hipLaunchKernelGGL(gcn_init,    dim3(16),  dim3(256), 0, stream, c1, Sg);
    hipLaunchKernelGGL(gcn_hist,    dim3(128), dim3(256), 0, stream, ei + EEDGES, c1);
    hipLaunchKernelGGL(gcn_scatter, dim3(128), dim3(256), 0, stream, ei, ei + EEDGES, x, c1, Sg);

    // build_z (12288 blocks) co-scheduled with W1 transpose (3072 tiles)
    hipLaunchKernelGGL(bz_tcvt1, dim3(15360), dim3(256), 0, stream,
                       x, c1, Sg, gw, gb, z, W1, W1t);

    // L1 GEMM 64x128 slice-per-XCD (1024 blocks first) + W2/W3 transpose in slack
    hipLaunchKernelGGL(gemmL1_tcvt23, dim3(4096), dim3(256), 0, stream,
                       z, W1t, P, W2, W2t, W3, W3t);
    hipLaunchKernelGGL((reduce_ep<true, true>),  dim3(1024), dim3(256), 0, stream, P, b1, (void*)z1, 512 * 2048, 2048, 8);

    // L2: z1[512,2048] @ W2 -> z2 (relu, bf16). 64^2 tile, S=2, chunk 1024, 512 blocks
    hipLaunchKernelGGL(gemm64, dim3(8, 32, 2), dim3(256), 0, stream, z1, W2t, P, 512, 2048, 2048, 1024);
    hipLaunchKernelGGL((reduce_ep<true, true>),  dim3(1024), dim3(256), 0, stream, P, b2, (void*)z2, 512 * 2048, 2048, 2);

    // L3: z2[512,2048] @ W3 -> out (f32). 64x128 slice-per-XCD-pair, S=4, 1024 blocks
    hipLaunchKernelGGL(gemm_L3, dim3(1024), dim3(256), 0, stream, z2, W3t, P);
    hipLaunchKernelGGL((reduce_ep<false, false>), dim3(2048), dim3(256), 0, stream, P, b3, (void*)out, 512 * 4096, 4096, 4);
}